// Round 3
// baseline (693.248 us; speedup 1.0000x reference)
//
#include <hip/hip_runtime.h>

// Topology encoder: 2-layer GCN (N=100k nodes, E=3.2M edges) + max/mean pool
// over B=64 graphs + 2-layer MLP. All fp32.
//
// CSR-by-dst built per call (hist -> scan -> place), then each GCN layer is a
// GATHER. k_place uses 8 edges/thread to pipeline returning atomics (latency-
// bound, not BW-bound). Gather unrolled x4 for MLP. Pool atomics wave-reduced.

#define F 32
#define POOLD 64
#define SCAN_CHUNK 1024   // 256 threads x 4 elements
#define EPT 8             // edges per thread in k_place

// ---- degree histogram over dst (fire-and-forget atomics, 4 edges/thread) ----
__global__ void k_hist(const int* __restrict__ ei, int* __restrict__ counts, int e) {
    int i = (blockIdx.x * blockDim.x + threadIdx.x) * 4;
    if (i + 4 <= e) {
        int4 d = *reinterpret_cast<const int4*>(ei + e + i);
        atomicAdd(&counts[d.x], 1);
        atomicAdd(&counts[d.y], 1);
        atomicAdd(&counts[d.z], 1);
        atomicAdd(&counts[d.w], 1);
    } else {
        for (int k = i; k < e; ++k) atomicAdd(&counts[ei[e + k]], 1);
    }
}

// ---- scan level 1 (+ fused dinv = rsqrt(deg+1)) ----
__global__ void k_scan1(const int* __restrict__ cnts, int* __restrict__ rp,
                        int* __restrict__ partial, float* __restrict__ dinv, int n) {
    __shared__ int lds[256];
    int base = blockIdx.x * SCAN_CHUNK;
    int t = threadIdx.x;
    int v[4];
    int s = 0;
#pragma unroll
    for (int j = 0; j < 4; ++j) {
        int i = base + t * 4 + j;
        v[j] = (i < n) ? cnts[i] : 0;
        if (i < n) dinv[i] = rsqrtf((float)v[j] + 1.0f);
        s += v[j];
    }
    lds[t] = s;
    __syncthreads();
    int val = s;
    for (int off = 1; off < 256; off <<= 1) {
        int other = (t >= off) ? lds[t - off] : 0;
        __syncthreads();
        val += other;
        lds[t] = val;
        __syncthreads();
    }
    int excl = val - s;
#pragma unroll
    for (int j = 0; j < 4; ++j) {
        int i = base + t * 4 + j;
        if (i < n) rp[i] = excl;
        excl += v[j];
    }
    if (t == 255) partial[blockIdx.x] = lds[255];
}

__global__ void k_scan2(int* __restrict__ partial, int nb) {
    __shared__ int lds[256];
    int t = threadIdx.x;
    int s = (t < nb) ? partial[t] : 0;
    lds[t] = s;
    __syncthreads();
    int val = s;
    for (int off = 1; off < 256; off <<= 1) {
        int other = (t >= off) ? lds[t - off] : 0;
        __syncthreads();
        val += other;
        lds[t] = val;
        __syncthreads();
    }
    if (t < nb) partial[t] = val - s;  // exclusive
}

__global__ void k_scan3(int* __restrict__ rp, const int* __restrict__ partial, int n) {
    int base = blockIdx.x * SCAN_CHUNK;
    int add = partial[blockIdx.x];
    int t = threadIdx.x;
#pragma unroll
    for (int j = 0; j < 4; ++j) {
        int i = base + t * 4 + j;
        if (i < n) rp[i] += add;
    }
}

// ---- CSR placement, 8 edges/thread: batch loads, 8 independent returning
// atomics in flight, then 8 stores. rowptr mutates start->end. ----
__global__ void k_place(const int* __restrict__ ei, int* __restrict__ rp,
                        int* __restrict__ col, int e) {
    int t0 = blockIdx.x * (blockDim.x * EPT) + threadIdx.x;
    int s[EPT], d[EPT], p[EPT];
#pragma unroll
    for (int k = 0; k < EPT; ++k) {
        int i = t0 + k * blockDim.x;
        if (i < e) { s[k] = ei[i]; d[k] = ei[e + i]; } else { d[k] = -1; }
    }
#pragma unroll
    for (int k = 0; k < EPT; ++k)
        if (d[k] >= 0) p[k] = atomicAdd(&rp[d[k]], 1);
#pragma unroll
    for (int k = 0; k < EPT; ++k)
        if (d[k] >= 0) col[p[k]] = s[k];
}

// ---- h0 = x @ W1  (K=3) ----
__global__ void k_xw1(const float* __restrict__ x, const float* __restrict__ W1,
                      float* __restrict__ h0, int n) {
    int i = blockIdx.x * blockDim.x + threadIdx.x;
    if (i >= n * F) return;
    int node = i >> 5, f = i & (F - 1);
    float x0 = x[node * 3 + 0], x1 = x[node * 3 + 1], x2 = x[node * 3 + 2];
    h0[i] = x0 * W1[f] + x1 * W1[F + f] + x2 * W1[2 * F + f];
}

// ---- g = h @ W2  (32x32) ----
__global__ void k_gemm2(const float* __restrict__ h, const float* __restrict__ W2,
                        float* __restrict__ g, int n) {
    int i = blockIdx.x * blockDim.x + threadIdx.x;
    if (i >= n * F) return;
    int node = i >> 5, f = i & (F - 1);
    const float* row = h + node * F;
    float acc = 0.0f;
#pragma unroll
    for (int k = 0; k < F; ++k) acc += row[k] * W2[k * F + f];
    g[i] = acc;
}

// ---- fused gather conv + bias + relu + pool; 8 threads/node, x4 unroll ----
__global__ void k_gather(const float* __restrict__ hin, const int* __restrict__ rp,
                         const int* __restrict__ col, const float* __restrict__ dinv,
                         const float* __restrict__ bias, const int* __restrict__ batch,
                         float* __restrict__ hout,
                         float* __restrict__ psum, float* __restrict__ pmax,
                         float* __restrict__ cnt, int n, int store, int do_cnt) {
    int t = blockIdx.x * blockDim.x + threadIdx.x;
    int node = t >> 3, q = t & 7;
    if (node >= n) return;
    int start = (node == 0) ? 0 : rp[node - 1];
    int end = rp[node];
    float dv = dinv[node];

    float4 acc = *reinterpret_cast<const float4*>(hin + node * F + q * 4);
    float dvv = dv * dv;
    acc.x *= dvv; acc.y *= dvv; acc.z *= dvv; acc.w *= dvv;

    int e = start;
    for (; e + 4 <= end; e += 4) {
        int s0 = col[e + 0], s1 = col[e + 1], s2 = col[e + 2], s3 = col[e + 3];
        float w0 = dinv[s0] * dv, w1 = dinv[s1] * dv,
              w2 = dinv[s2] * dv, w3 = dinv[s3] * dv;
        float4 v0 = *reinterpret_cast<const float4*>(hin + s0 * F + q * 4);
        float4 v1 = *reinterpret_cast<const float4*>(hin + s1 * F + q * 4);
        float4 v2 = *reinterpret_cast<const float4*>(hin + s2 * F + q * 4);
        float4 v3 = *reinterpret_cast<const float4*>(hin + s3 * F + q * 4);
        acc.x += v0.x * w0 + v1.x * w1 + v2.x * w2 + v3.x * w3;
        acc.y += v0.y * w0 + v1.y * w1 + v2.y * w2 + v3.y * w3;
        acc.z += v0.z * w0 + v1.z * w1 + v2.z * w2 + v3.z * w3;
        acc.w += v0.w * w0 + v1.w * w1 + v2.w * w2 + v3.w * w3;
    }
    for (; e < end; ++e) {
        int s = col[e];
        float wv = dinv[s] * dv;
        const float4 v = *reinterpret_cast<const float4*>(hin + s * F + q * 4);
        acc.x += v.x * wv; acc.y += v.y * wv; acc.z += v.z * wv; acc.w += v.w * wv;
    }

    const float4 b4 = *reinterpret_cast<const float4*>(bias + q * 4);
    float4 v;
    v.x = fmaxf(acc.x + b4.x, 0.0f);
    v.y = fmaxf(acc.y + b4.y, 0.0f);
    v.z = fmaxf(acc.z + b4.z, 0.0f);
    v.w = fmaxf(acc.w + b4.w, 0.0f);
    if (store) *reinterpret_cast<float4*>(hout + node * F + q * 4) = v;

    int b = batch[node];
    int lane = threadIdx.x & 63;
    int bFirst = __shfl(b, 0);
    int bLast  = __shfl(b, 63);
    if (bFirst == bLast) {
        float4 sv = v, mv = v;
        for (int off = 8; off < 64; off <<= 1) {
            sv.x += __shfl_down(sv.x, off);
            sv.y += __shfl_down(sv.y, off);
            sv.z += __shfl_down(sv.z, off);
            sv.w += __shfl_down(sv.w, off);
            mv.x = fmaxf(mv.x, __shfl_down(mv.x, off));
            mv.y = fmaxf(mv.y, __shfl_down(mv.y, off));
            mv.z = fmaxf(mv.z, __shfl_down(mv.z, off));
            mv.w = fmaxf(mv.w, __shfl_down(mv.w, off));
        }
        if (lane < 8) {
            float* ps = psum + b * F + lane * 4;
            atomicAdd(ps + 0, sv.x);
            atomicAdd(ps + 1, sv.y);
            atomicAdd(ps + 2, sv.z);
            atomicAdd(ps + 3, sv.w);
            int* pm = reinterpret_cast<int*>(pmax + b * F + lane * 4);
            atomicMax(pm + 0, __float_as_int(mv.x));
            atomicMax(pm + 1, __float_as_int(mv.y));
            atomicMax(pm + 2, __float_as_int(mv.z));
            atomicMax(pm + 3, __float_as_int(mv.w));
            if (do_cnt && lane == 0) atomicAdd(&cnt[b], 8.0f);
        }
    } else {
        float* ps = psum + b * F + q * 4;
        atomicAdd(ps + 0, v.x);
        atomicAdd(ps + 1, v.y);
        atomicAdd(ps + 2, v.z);
        atomicAdd(ps + 3, v.w);
        int* pm = reinterpret_cast<int*>(pmax + b * F + q * 4);
        atomicMax(pm + 0, __float_as_int(v.x));
        atomicMax(pm + 1, __float_as_int(v.y));
        atomicMax(pm + 2, __float_as_int(v.z));
        atomicMax(pm + 3, __float_as_int(v.w));
        if (do_cnt && q == 0) atomicAdd(&cnt[b], 1.0f);
    }
}

// ---- fused MLP head: one block per graph (64 threads) ----
__global__ void k_mlp(const float* __restrict__ sum1, const float* __restrict__ max1,
                      const float* __restrict__ sum2, const float* __restrict__ max2,
                      const float* __restrict__ cnt,
                      const float* __restrict__ LW1, const float* __restrict__ Lb1,
                      const float* __restrict__ LW2, const float* __restrict__ Lb2,
                      float* __restrict__ out, int outd) {
    __shared__ float zs[POOLD];
    int b = blockIdx.x, j = threadIdx.x;  // blockDim.x == 64
    float invc = 1.0f / fmaxf(cnt[b], 1.0f);
    float acc = Lb1[j];
#pragma unroll
    for (int i = 0; i < POOLD; ++i) {
        float s;
        if (i < F) s = max1[b * F + i] + max2[b * F + i];
        else       s = (sum1[b * F + i - F] + sum2[b * F + i - F]) * invc;
        acc += s * LW1[i * POOLD + j];
    }
    zs[j] = fmaxf(acc, 0.0f);
    __syncthreads();
    if (j < outd) {
        float a2 = Lb2[j];
#pragma unroll
        for (int jj = 0; jj < POOLD; ++jj) a2 += zs[jj] * LW2[jj * outd + j];
        out[b * outd + j] = a2;
    }
}

extern "C" void kernel_launch(void* const* d_in, const int* in_sizes, int n_in,
                              void* d_out, int out_size, void* d_ws, size_t ws_size,
                              hipStream_t stream) {
    const float* x    = (const float*)d_in[0];
    const int*   ei   = (const int*)d_in[1];
    const int*   batch= (const int*)d_in[2];
    const float* W1   = (const float*)d_in[3];
    const float* b1   = (const float*)d_in[4];
    const float* W2   = (const float*)d_in[5];
    const float* b2   = (const float*)d_in[6];
    const float* LW1  = (const float*)d_in[7];
    const float* Lb1  = (const float*)d_in[8];
    const float* LW2  = (const float*)d_in[9];
    const float* Lb2  = (const float*)d_in[10];
    float* out = (float*)d_out;

    const int N = in_sizes[0] / 3;
    const int E = in_sizes[1] / 2;
    const int OUTD = in_sizes[10];
    const int B = out_size / OUTD;
    const int poolsz = 4 * B * F + B;

    // ---- workspace layout: [counts][pools] contiguous for one memset ----
    char* p = (char*)d_ws;
    int* counts = (int*)p;            p += (size_t)N * 4;
    float* pools= (float*)p;          p += (size_t)poolsz * 4;
    int* rowptr = (int*)p;            p += (size_t)N * 4;
    int* col    = (int*)p;            p += (size_t)E * 4;
    int* partial= (int*)p;            p += 256 * 4;
    float* dinv = (float*)p;          p += (size_t)N * 4;
    float* buf0 = (float*)p;          p += (size_t)N * F * 4;
    float* buf1 = (float*)p;          p += (size_t)N * F * 4;
    float* sum1 = pools;
    float* max1 = sum1 + B * F;
    float* sum2 = max1 + B * F;
    float* max2 = sum2 + B * F;
    float* cnt  = max2 + B * F;

    const int BS = 256;
    auto g1 = [&](long long n) { return (int)((n + BS - 1) / BS); };
    const int nScanBlocks = (N + SCAN_CHUNK - 1) / SCAN_CHUNK;

    // CSR build + norms
    hipMemsetAsync(counts, 0, (size_t)(N + poolsz) * 4, stream);
    k_hist<<<g1((E + 3) / 4), BS, 0, stream>>>(ei, counts, E);
    k_scan1<<<nScanBlocks, 256, 0, stream>>>(counts, rowptr, partial, dinv, N);
    k_scan2<<<1, 256, 0, stream>>>(partial, nScanBlocks);
    k_scan3<<<nScanBlocks, 256, 0, stream>>>(rowptr, partial, N);
    k_place<<<(int)((E + (long long)BS * EPT - 1) / ((long long)BS * EPT)), BS, 0, stream>>>(
        ei, rowptr, col, E);  // rowptr -> row ends

    // layer 1
    k_xw1<<<g1((long long)N * F), BS, 0, stream>>>(x, W1, buf0, N);
    k_gather<<<g1((long long)N * 8), BS, 0, stream>>>(buf0, rowptr, col, dinv, b1,
                                                      batch, buf1, sum1, max1, cnt,
                                                      N, /*store=*/1, /*do_cnt=*/1);
    // layer 2
    k_gemm2<<<g1((long long)N * F), BS, 0, stream>>>(buf1, W2, buf0, N);
    k_gather<<<g1((long long)N * 8), BS, 0, stream>>>(buf0, rowptr, col, dinv, b2,
                                                      batch, buf1, sum2, max2, cnt,
                                                      N, /*store=*/0, /*do_cnt=*/0);

    // MLP head
    k_mlp<<<B, 64, 0, stream>>>(sum1, max1, sum2, max2, cnt,
                                LW1, Lb1, LW2, Lb2, out, OUTD);
}